// Round 5
// baseline (162.598 us; speedup 1.0000x reference)
//
#include <hip/hip_runtime.h>
#include <math.h>

#define SEQL 256

struct PF {
    const float* norm_b;
    const float* in_proj_w;
    const float* conv_w[3];
    const float* conv_b[3];
    const float* xproj_w[3];
    const float* dtproj_w[3];
    const float* dtproj_b[3];
    const float* A_log[3];
    const float* Dskip[3];
    const float* out_proj_w;
    const float* w1; const float* b1;
    const float* w2; const float* b2;
    const float* w3; const float* b3;
    float4* out4;
};

__device__ __forceinline__ float silu_f(float x)     { return x / (1.0f + expf(-x)); }
__device__ __forceinline__ float softplus_f(float x) { return x > 0.f ? x + log1pf(expf(-x)) : log1pf(expf(x)); }
__device__ __forceinline__ float elu_f(float x)      { return x > 0.f ? x : expm1f(x); }

// ---------------------------------------------------------------------------
// Single dispatch: each of 100 blocks (256 threads) redundantly computes the
// entire batch-constant pipeline (scan is register-constant fma chains; MLP
// weights total 1.1 MB and are L2-broadcast across blocks), then writes its
// 2048-float4 slice of the 8192x100 output. No grid sync, no ws round-trips.
// ---------------------------------------------------------------------------
__global__ __launch_bounds__(256) void k_fused(PF p) {
    __shared__ float xs_c[3][4][2];   // [dir][class][d] post-conv silu'd x
    __shared__ float dl_c[3][4][2];   // [dir][class][d] delta
    __shared__ float hc[SEQL][49];    // q = (dir*2+d)*8 + k  (49-pad: conflict-free)
    __shared__ __align__(16) float yrow[SEQL];
    __shared__ __align__(16) float h1s[512];
    __shared__ __align__(16) float h2s[256];
    __shared__ __align__(16) float rowL[100];

    const int tid = threadIdx.x;
    const float nb0 = p.norm_b[0];                  // LayerNorm over singleton axis == norm_b
    const float c0  = nb0 * p.in_proj_w[0];
    const float c1  = nb0 * p.in_proj_w[1];

    // ---- Phase A: 12 threads compute the 4 l-classes (l=0,1,2,>=3) ----
    if (tid < 12) {
        const int dir = tid >> 2, cls = tid & 3;
        const float* cw  = p.conv_w[dir];
        const float* cb  = p.conv_b[dir];
        const float* xp  = p.xproj_w[dir];
        const float* dtw = p.dtproj_w[dir];
        const float* dtb = p.dtproj_b[dir];
        float xsv[2];
        for (int d = 0; d < 2; ++d) {
            float s = 0.f;                           // same k-ascending order as reference
            for (int k = 3 - cls; k < 4; ++k) s += cw[d * 4 + k];
            xsv[d] = silu_f((d == 0 ? c0 : c1) * s + cb[d]);
            xs_c[dir][cls][d] = xsv[d];
        }
        const float xd0 = xp[0] * xsv[0] + xp[1] * xsv[1];   // DT_RANK = 1
        dl_c[dir][cls][0] = softplus_f(dtw[0] * xd0 + dtb[0]);
        dl_c[dir][cls][1] = softplus_f(dtw[1] * xd0 + dtb[1]);
    }
    __syncthreads();

    // ---- Phase B: 48 threads x 2 recurrences, register-constant for l>=3 ----
    if (tid < 48) {
        const int dir = tid / 16;
        const int r   = tid % 16;
        const int d   = r / 8;
        const int k   = r % 8;
        const int n0  = 2 * k, n1 = 2 * k + 1;
        const float* xp = p.xproj_w[dir];
        const float A0 = -expf(p.A_log[dir][d * 16 + n0]);
        const float A1 = -expf(p.A_log[dir][d * 16 + n1]);
        const float b00 = xp[(1 + n0) * 2],  b01 = xp[(1 + n0) * 2 + 1];
        const float b10 = xp[(1 + n1) * 2],  b11 = xp[(1 + n1) * 2 + 1];
        const float c00 = xp[(17 + n0) * 2], c01 = xp[(17 + n0) * 2 + 1];
        const float c10 = xp[(17 + n1) * 2], c11 = xp[(17 + n1) * 2 + 1];
        const int q = (dir * 2 + d) * 8 + k;

        float e0[4], f0[4], e1[4], f1[4], cp0[4], cp1[4];
        #pragma unroll
        for (int cls = 0; cls < 4; ++cls) {
            const float x0 = xs_c[dir][cls][0], x1 = xs_c[dir][cls][1];
            const float dlt = dl_c[dir][cls][d];
            const float u   = (d == 0) ? x0 : x1;
            const float du  = dlt * u;
            e0[cls] = expf(dlt * A0);  f0[cls] = du * (b00 * x0 + b01 * x1);
            e1[cls] = expf(dlt * A1);  f1[cls] = du * (b10 * x0 + b11 * x1);
            cp0[cls] = c00 * x0 + c01 * x1;
            cp1[cls] = c10 * x0 + c11 * x1;
        }
        float h0 = 0.f, h1v = 0.f;
        #pragma unroll
        for (int l = 0; l < 3; ++l) {               // classes 0..2, static indices
            h0  = e0[l] * h0  + f0[l];
            h1v = e1[l] * h1v + f1[l];
            hc[l][q] = h0 * cp0[l] + h1v * cp1[l];
        }
        const float E0 = e0[3], F0 = f0[3], E1 = e1[3], F1 = f1[3];
        const float P0 = cp0[3], P1 = cp1[3];
        for (int l = 3; l < SEQL; ++l) {            // two interleaved fma chains
            h0  = E0 * h0  + F0;
            h1v = E1 * h1v + F1;
            hc[l][q] = h0 * P0 + h1v * P1;
        }
    }
    __syncthreads();

    // ---- Phase C: reduce over n, Dskip/silu(z)/out_proj + l-permutations ----
    {
        const int t = tid;
        const float opw0 = p.out_proj_w[0], opw1 = p.out_proj_w[1];
        const float sz0  = silu_f(nb0 * p.in_proj_w[2]);
        const float sz1  = silu_f(nb0 * p.in_proj_w[3]);
        float acc = 0.f;
        for (int dir = 0; dir < 3; ++dir) {
            int lv;
            if      (dir == 0) lv = t;                          // forward
            else if (dir == 1) lv = SEQL - 1 - t;               // backward
            else               lv = ((t & 3) << 6) + (t >> 2);  // slice perm inverse
            const int cls = lv < 3 ? lv : 3;
            float s0 = 0.f, s1 = 0.f;
            for (int k = 0; k < 8; ++k) {
                s0 += hc[lv][dir * 16 + k];
                s1 += hc[lv][dir * 16 + 8 + k];
            }
            const float y0 = (s0 + xs_c[dir][cls][0] * p.Dskip[dir][0]) * sz0;
            const float y1 = (s1 + xs_c[dir][cls][1] * p.Dskip[dir][1]) * sz1;
            acc += opw0 * y0 + opw1 * y1;
        }
        yrow[t] = acc;
    }
    __syncthreads();

    // ---- MLP1: thread t -> rows t and t+256 (w1 L2-broadcast) ----
    {
        const float4* y4 = reinterpret_cast<const float4*>(yrow);
        #pragma unroll
        for (int rr = 0; rr < 2; ++rr) {
            const int j = tid + rr * 256;
            const float4* wr = reinterpret_cast<const float4*>(p.w1 + j * 256);
            float s = 0.f;
            #pragma unroll 8
            for (int k = 0; k < 64; ++k) {
                const float4 w = wr[k], y = y4[k];
                s += w.x * y.x + w.y * y.y + w.z * y.z + w.w * y.w;
            }
            h1s[j] = elu_f(s + p.b1[j]);
        }
    }
    __syncthreads();

    // ---- MLP2: thread t -> row t ----
    {
        const float4* h4 = reinterpret_cast<const float4*>(h1s);
        const float4* wr = reinterpret_cast<const float4*>(p.w2 + tid * 512);
        float s = 0.f;
        #pragma unroll 8
        for (int k = 0; k < 128; ++k) {
            const float4 w = wr[k], h = h4[k];
            s += w.x * h.x + w.y * h.y + w.z * h.z + w.w * h.w;
        }
        h2s[tid] = elu_f(s + p.b2[tid]);
    }
    __syncthreads();

    // ---- MLP3: threads 0..99 -> row[100] ----
    if (tid < 100) {
        const float4* h4 = reinterpret_cast<const float4*>(h2s);
        const float4* wr = reinterpret_cast<const float4*>(p.w3 + tid * 256);
        float s = 0.f;
        #pragma unroll 8
        for (int k = 0; k < 64; ++k) {
            const float4 w = wr[k], h = h4[k];
            s += w.x * h.x + w.y * h.y + w.z * h.z + w.w * h.w;
        }
        rowL[tid] = s + p.b3[tid];
    }
    __syncthreads();

    // ---- Broadcast: this block's 2048-float4 slice (8 x 256) ----
    {
        const float4* rowL4 = reinterpret_cast<const float4*>(rowL);
        const int base = blockIdx.x * 2048;
        #pragma unroll
        for (int i = 0; i < 8; ++i) {
            const int idx = base + i * 256 + tid;
            p.out4[idx] = rowL4[idx % 25];
        }
    }
}

extern "C" void kernel_launch(void* const* d_in, const int* in_sizes, int n_in,
                              void* d_out, int out_size, void* d_ws, size_t ws_size,
                              hipStream_t stream) {
    const float* const* in = (const float* const*)d_in;
    PF p;
    p.norm_b    = in[2];
    p.in_proj_w = in[3];
    for (int dir = 0; dir < 3; ++dir) {
        const int base = 4 + dir * 7;
        p.conv_w[dir]   = in[base + 0];
        p.conv_b[dir]   = in[base + 1];
        p.xproj_w[dir]  = in[base + 2];
        p.dtproj_w[dir] = in[base + 3];
        p.dtproj_b[dir] = in[base + 4];
        p.A_log[dir]    = in[base + 5];
        p.Dskip[dir]    = in[base + 6];
    }
    p.out_proj_w = in[25];
    p.w1 = in[26]; p.b1 = in[27];
    p.w2 = in[28]; p.b2 = in[29];
    p.w3 = in[30]; p.b3 = in[31];
    p.out4 = (float4*)d_out;

    // 100 blocks x 2048 float4 = 204800 float4 = 8192 x 100 floats
    k_fused<<<100, 256, 0, stream>>>(p);
}